// Round 4
// baseline (404.818 us; speedup 1.0000x reference)
//
#include <hip/hip_runtime.h>
#include <hip/hip_bf16.h>

#define B_   2
#define L_   2048
#define D_   2048
#define H_   32
#define HKV_ 8
#define HD_  64
#define G_   4
#define M_   4096   // B_*L_
#define NF_  3072   // fused QKV output width

typedef __attribute__((ext_vector_type(8))) short bf16x8;
typedef __attribute__((ext_vector_type(4))) float f32x4;

static __device__ __forceinline__ unsigned short f2bf(float f) {
  unsigned int u = __float_as_uint(f);
  unsigned int r = (u + 0x7FFFu + ((u >> 16) & 1u)) >> 16;
  return (unsigned short)r;
}
static __device__ __forceinline__ unsigned short f2bf_hw(float f) {
  __hip_bfloat16 h = __float2bfloat16(f);
  return *(unsigned short*)&h;
}

#define GLD16(g, l) __builtin_amdgcn_global_load_lds(                      \
    (const __attribute__((address_space(1))) void*)(g),                    \
    (__attribute__((address_space(3))) void*)(l), 16, 0, 0)

// ---------------- elementwise cast f32 -> bf16 (x4 vectorized) ----------------
__global__ void cast_bf16_kernel(const float* __restrict__ in,
                                 unsigned short* __restrict__ out, int n4) {
  int i = blockIdx.x * blockDim.x + threadIdx.x;
  if (i >= n4) return;
  float4 v = ((const float4*)in)[i];
  uint2 r;
  r.x = (unsigned int)f2bf(v.x) | ((unsigned int)f2bf(v.y) << 16);
  r.y = (unsigned int)f2bf(v.z) | ((unsigned int)f2bf(v.w) << 16);
  ((uint2*)out)[i] = r;
}

// ---------------- transpose+cast: src[K][N] f32 -> dst[N][K] bf16 ----------------
__global__ void transpose_cast_kernel(const float* __restrict__ src,
                                      unsigned short* __restrict__ dst,
                                      int K, int N) {
  __shared__ float tile[32][33];
  int k0 = blockIdx.y * 32, n0 = blockIdx.x * 32;
  int tx = threadIdx.x, ty = threadIdx.y;  // (32,8)
#pragma unroll
  for (int r = 0; r < 4; ++r)
    tile[ty * 4 + r][tx] = src[(size_t)(k0 + ty * 4 + r) * N + n0 + tx];
  __syncthreads();
#pragma unroll
  for (int r = 0; r < 4; ++r)
    dst[(size_t)(n0 + ty * 4 + r) * K + k0 + tx] = f2bf(tile[tx][ty * 4 + r]);
}

// ---------------- 256x256 8-phase GEMM: C[M][N] f32 = A[M][K]bf16 * Bt[N][K]bf16 ----------------
// BK=64, 8 waves (2Mx4N), wave tile 128x64, double-buffered 128KiB LDS,
// st_16x32 XOR swizzle (both-sides: pre-swizzled global source + swizzled reads),
// issue-early staging (A @phase0, B @phase1), single vmcnt(0) @phase3, setprio MFMA.
__global__ __launch_bounds__(512, 2)
void gemm256_kernel(const unsigned short* __restrict__ A,
                    const unsigned short* __restrict__ Bt,
                    float* __restrict__ C, int M, int N, int K) {
  extern __shared__ unsigned short lds[];
  const int tid = threadIdx.x;
  const int w = tid >> 6, l = tid & 63;
  const int wave_m = w >> 2, wave_n = w & 3;
  const int fr = l & 15, hi = l >> 4;
  const int row0 = blockIdx.y * 256, col0 = blockIdx.x * 256;
  const int NT = K >> 6;

  // staging coords: wave w stages chunks {w, 8+w} of each 128x64 half-tile
  // chunk c covers rows c*8..c*8+7; lane covers row c*8+(l>>3), colgrp l&7
  const int lr0 = w * 8 + (l >> 3);        // rows 0..63   (chunk w)
  const int lr1 = 64 + lr0;                // rows 64..127 (chunk 8+w)
  const int sc0 = (((l & 7) ^ (((lr0 >> 2) & 1) << 1)) << 3);  // swizzled src col
  const int sc1 = (((l & 7) ^ (((lr1 >> 2) & 1) << 1)) << 3);

  // read-side swizzle key (row bit2 -> flip 16 elements)
  const int sw = ((fr >> 2) & 1) << 4;

  f32x4 acc[8][4];
#pragma unroll
  for (int m = 0; m < 8; ++m)
#pragma unroll
    for (int n = 0; n < 4; ++n) acc[m][n] = (f32x4){0.f, 0.f, 0.f, 0.f};

#define STAGE_A(buf_, kt_) do {                                                \
    const int base_ = (buf_) * 16384;                                          \
    GLD16(A + (size_t)(row0 + lr0) * K + (kt_) * 64 + sc0,                     \
          &lds[base_ + w * 512]);                                              \
    GLD16(A + (size_t)(row0 + lr1) * K + (kt_) * 64 + sc1,                     \
          &lds[base_ + (8 + w) * 512]);                                        \
    GLD16(A + (size_t)(row0 + 128 + lr0) * K + (kt_) * 64 + sc0,               \
          &lds[base_ + 8192 + w * 512]);                                       \
    GLD16(A + (size_t)(row0 + 128 + lr1) * K + (kt_) * 64 + sc1,               \
          &lds[base_ + 8192 + (8 + w) * 512]);                                 \
  } while (0)
#define STAGE_B(buf_, kt_) do {                                                \
    const int base_ = 32768 + (buf_) * 16384;                                  \
    GLD16(Bt + (size_t)(col0 + lr0) * K + (kt_) * 64 + sc0,                    \
          &lds[base_ + w * 512]);                                              \
    GLD16(Bt + (size_t)(col0 + lr1) * K + (kt_) * 64 + sc1,                    \
          &lds[base_ + (8 + w) * 512]);                                        \
    GLD16(Bt + (size_t)(col0 + 128 + lr0) * K + (kt_) * 64 + sc0,              \
          &lds[base_ + 8192 + w * 512]);                                       \
    GLD16(Bt + (size_t)(col0 + 128 + lr1) * K + (kt_) * 64 + sc1,              \
          &lds[base_ + 8192 + (8 + w) * 512]);                                 \
  } while (0)

  // prologue: stage tile 0 into buf 0
  STAGE_A(0, 0);
  STAGE_B(0, 0);
  asm volatile("s_waitcnt vmcnt(0)" ::: "memory");
  __builtin_amdgcn_s_barrier();

  bf16x8 bfrag[4][2];
  const int brow = (wave_n & 1) * 64;

  for (int kt = 0; kt < NT; ++kt) {
    const int buf = kt & 1;
    const int ab = buf * 16384 + wave_m * 8192;
    const int bb = 32768 + buf * 16384 + (wave_n >> 1) * 8192 + brow * 64;
#pragma unroll
    for (int p = 0; p < 4; ++p) {
      if (p == 0) {
#pragma unroll
        for (int nf = 0; nf < 4; ++nf)
#pragma unroll
          for (int kk = 0; kk < 2; ++kk)
            bfrag[nf][kk] = *(const bf16x8*)
                &lds[bb + (nf * 16 + fr) * 64 + ((kk * 32 + hi * 8) ^ sw)];
      }
      bf16x8 afrag[2][2];
#pragma unroll
      for (int mi = 0; mi < 2; ++mi)
#pragma unroll
        for (int kk = 0; kk < 2; ++kk)
          afrag[mi][kk] = *(const bf16x8*)
              &lds[ab + ((p * 2 + mi) * 16 + fr) * 64 + ((kk * 32 + hi * 8) ^ sw)];
      if (kt + 1 < NT) {
        if (p == 0) STAGE_A(buf ^ 1, kt + 1);
        else if (p == 1) STAGE_B(buf ^ 1, kt + 1);
      }
      __builtin_amdgcn_s_barrier();
      __builtin_amdgcn_s_setprio(1);
#pragma unroll
      for (int mi = 0; mi < 2; ++mi)
#pragma unroll
        for (int nf = 0; nf < 4; ++nf)
#pragma unroll
          for (int kk = 0; kk < 2; ++kk)
            acc[p * 2 + mi][nf] = __builtin_amdgcn_mfma_f32_16x16x32_bf16(
                afrag[mi][kk], bfrag[nf][kk], acc[p * 2 + mi][nf], 0, 0, 0);
      __builtin_amdgcn_s_setprio(0);
      if (p == 3) asm volatile("s_waitcnt vmcnt(0)" ::: "memory");
      __builtin_amdgcn_s_barrier();
    }
  }

#pragma unroll
  for (int m = 0; m < 8; ++m)
#pragma unroll
    for (int n = 0; n < 4; ++n)
#pragma unroll
      for (int j = 0; j < 4; ++j) {
        int r = row0 + wave_m * 128 + m * 16 + hi * 4 + j;
        int c = col0 + wave_n * 64 + n * 16 + fr;
        C[(size_t)r * N + c] = acc[m][n][j];
      }
#undef STAGE_A
#undef STAGE_B
}

// ---------------- RoPE: src[M][3072] f32 (+col_off) -> dst[B][nh][L][64] bf16 ----------------
__global__ void rope_kernel(const float* __restrict__ src,
                            const float* __restrict__ cosf,
                            const float* __restrict__ sinf,
                            unsigned short* __restrict__ dst, int nh, int col_off,
                            float scale, int total) {
  int idx = blockIdx.x * blockDim.x + threadIdx.x;
  if (idx >= total) return;
  int i = idx & 31;
  int h = (idx >> 5) & (nh - 1);
  int row = idx / (nh << 5);
  int lpos = row & (L_ - 1);
  int b = row >> 11;
  const float* s = src + (size_t)row * NF_ + col_off + h * 64 + 2 * i;
  float tr = s[0], ti = s[1];
  float c = cosf[lpos * 32 + i], sn = sinf[lpos * 32 + i];
  float orr = (tr * c - ti * sn) * scale;
  float oii = (tr * sn + ti * c) * scale;
  size_t o = (((size_t)(b * nh + h)) * L_ + lpos) * 64 + 2 * i;
  unsigned int packed = (unsigned int)f2bf(orr) | ((unsigned int)f2bf(oii) << 16);
  *(unsigned int*)&dst[o] = packed;
}

// ---------------- V transpose (LDS-tiled): qkv_f v-cols -> vT[B][HKV][64][L] bf16 ----------------
__global__ void cast_vT_kernel(const float* __restrict__ v,
                               unsigned short* __restrict__ vT) {
  __shared__ float tile[32][33];
  int l0 = blockIdx.x * 32, d0 = blockIdx.y * 32;
  int z = blockIdx.z;                 // b*8+hkv
  int b = z >> 3, hkv = z & 7;
  int tx = threadIdx.x, ty = threadIdx.y;  // (32,8)
  const float* src = v + (size_t)(b * L_) * NF_ + 2560 + hkv * 64;
#pragma unroll
  for (int r = 0; r < 4; ++r)
    tile[ty * 4 + r][tx] = src[(size_t)(l0 + ty * 4 + r) * NF_ + d0 + tx];
  __syncthreads();
  unsigned short* dst = vT + ((size_t)z * 64) * L_;
#pragma unroll
  for (int r = 0; r < 4; ++r)
    dst[(size_t)(d0 + ty * 4 + r) * L_ + l0 + tx] = f2bf(tile[tx][ty * 4 + r]);
}

// ---------------- Flash attention (as R3, + setprio around MFMA) ----------------
__global__ __launch_bounds__(256)
void attn_kernel(const unsigned short* __restrict__ Q,   // [B][H][L][64] (pre-scaled)
                 const unsigned short* __restrict__ Kt,  // [B][HKV][L][64]
                 const unsigned short* __restrict__ Vt,  // [B][HKV][64][L]
                 unsigned short* __restrict__ O) {       // [B*L][H*64]
  __shared__ unsigned short Kl[64 * 64];
  __shared__ unsigned short Vl[64 * 64];
  __shared__ unsigned short Pl[64 * 64];
  const int tid = threadIdx.x, w = tid >> 6, l = tid & 63;
  const int bh = blockIdx.x;
  const int b = bh >> 5, h = bh & 31;
  const int hkv = h >> 2;
  const int pair = blockIdx.y;
  const int fr = l & 15, hi = l >> 4;
  const int frx = fr & 7;

  const int srow = l >> 3;
  const int scole = ((l & 7) ^ srow) * 8;

  const unsigned short* kbase = Kt + ((size_t)(b * HKV_ + hkv)) * L_ * 64;
  const unsigned short* vbase = Vt + ((size_t)(b * HKV_ + hkv)) * 64 * L_;

  for (int half = 0; half < 2; ++half) {
    const int by = half ? (15 - pair) : pair;
    const int q0 = by * 128;

    bf16x8 qf[2][2];
#pragma unroll
    for (int s = 0; s < 2; ++s) {
      const unsigned short* qb =
          Q + (((size_t)bh) * L_ + q0 + s * 64 + w * 16 + fr) * 64 + hi * 8;
      qf[s][0] = *(const bf16x8*)(qb);
      qf[s][1] = *(const bf16x8*)(qb + 32);
    }

    float m_i[2][4], l_p[2][4];
    f32x4 oacc[2][4];
#pragma unroll
    for (int s = 0; s < 2; ++s)
#pragma unroll
      for (int j = 0; j < 4; ++j) { m_i[s][j] = -1e30f; l_p[s][j] = 0.f; }
#pragma unroll
    for (int s = 0; s < 2; ++s)
#pragma unroll
      for (int nf = 0; nf < 4; ++nf) oacc[s][nf] = (f32x4){0.f, 0.f, 0.f, 0.f};

    const int nt = 2 * by + 2;

    for (int t = 0; t < nt; ++t) {
      const int kv0 = t * 64;
#pragma unroll
      for (int u = 0; u < 2; ++u) {
        const int c = w * 2 + u;
        const int rr = c * 8 + srow;
        GLD16(kbase + ((size_t)(kv0 + rr)) * 64 + scole, &Kl[c * 512]);
        GLD16(vbase + ((size_t)rr) * L_ + kv0 + scole, &Vl[c * 512]);
      }
      __syncthreads();

#pragma unroll
      for (int s = 0; s < 2; ++s) {
        const int dlim = 2 * by + s;
        if (t > dlim) continue;

        f32x4 sacc[4];
#pragma unroll
        for (int nf = 0; nf < 4; ++nf) sacc[nf] = (f32x4){0.f, 0.f, 0.f, 0.f};
        __builtin_amdgcn_s_setprio(1);
#pragma unroll
        for (int ks = 0; ks < 2; ++ks) {
#pragma unroll
          for (int nf = 0; nf < 4; ++nf) {
            bf16x8 kfrag = *(const bf16x8*)
                &Kl[(nf * 16 + fr) * 64 + (((ks * 4 + hi) ^ frx) * 8)];
            sacc[nf] = __builtin_amdgcn_mfma_f32_16x16x32_bf16(qf[s][ks], kfrag, sacc[nf], 0, 0, 0);
          }
        }
        __builtin_amdgcn_s_setprio(0);

        if (t == dlim) {
          const int rbase = q0 + s * 64 + w * 16 + hi * 4;
#pragma unroll
          for (int nf = 0; nf < 4; ++nf)
#pragma unroll
            for (int j = 0; j < 4; ++j)
              if (kv0 + nf * 16 + fr > rbase + j) sacc[nf][j] = -1e30f;
        }

        float rowmax[4];
#pragma unroll
        for (int j = 0; j < 4; ++j) {
          float mx = fmaxf(fmaxf(sacc[0][j], sacc[1][j]),
                           fmaxf(sacc[2][j], sacc[3][j]));
          mx = fmaxf(mx, __shfl_xor(mx, 1));
          mx = fmaxf(mx, __shfl_xor(mx, 2));
          mx = fmaxf(mx, __shfl_xor(mx, 4));
          mx = fmaxf(mx, __shfl_xor(mx, 8));
          rowmax[j] = mx;
        }

        float g = rowmax[0] - m_i[s][0];
        g = fmaxf(g, rowmax[1] - m_i[s][1]);
        g = fmaxf(g, rowmax[2] - m_i[s][2]);
        g = fmaxf(g, rowmax[3] - m_i[s][3]);
        if (!__all(g <= 8.f)) {
#pragma unroll
          for (int j = 0; j < 4; ++j) {
            float mnew = fmaxf(m_i[s][j], rowmax[j]);
            float cr = exp2f(m_i[s][j] - mnew);
            m_i[s][j] = mnew;
            l_p[s][j] *= cr;
#pragma unroll
            for (int nf = 0; nf < 4; ++nf) oacc[s][nf][j] *= cr;
          }
        }

#pragma unroll
        for (int j = 0; j < 4; ++j) {
          const int prow = w * 16 + hi * 4 + j;
#pragma unroll
          for (int nf = 0; nf < 4; ++nf) {
            float p = exp2f(sacc[nf][j] - m_i[s][j]);
            l_p[s][j] += p;
            Pl[prow * 64 + (((nf * 2 + (fr >> 3)) ^ (prow & 7)) * 8) + frx] =
                f2bf_hw(p);
          }
        }

        __builtin_amdgcn_s_setprio(1);
#pragma unroll
        for (int ks = 0; ks < 2; ++ks) {
          bf16x8 pa = *(const bf16x8*)
              &Pl[(w * 16 + fr) * 64 + (((ks * 4 + hi) ^ frx) * 8)];
#pragma unroll
          for (int nf = 0; nf < 4; ++nf) {
            bf16x8 vfrag = *(const bf16x8*)
                &Vl[(nf * 16 + fr) * 64 + (((ks * 4 + hi) ^ frx) * 8)];
            oacc[s][nf] = __builtin_amdgcn_mfma_f32_16x16x32_bf16(pa, vfrag, oacc[s][nf], 0, 0, 0);
          }
        }
        __builtin_amdgcn_s_setprio(0);
      }
      __syncthreads();
    }

#pragma unroll
    for (int s = 0; s < 2; ++s)
#pragma unroll
      for (int j = 0; j < 4; ++j) {
        float lsum = l_p[s][j];
        lsum += __shfl_xor(lsum, 1);
        lsum += __shfl_xor(lsum, 2);
        lsum += __shfl_xor(lsum, 4);
        lsum += __shfl_xor(lsum, 8);
        float inv = 1.0f / lsum;
#pragma unroll
        for (int nf = 0; nf < 4; ++nf) {
          int qrow = q0 + s * 64 + w * 16 + hi * 4 + j;
          int d = nf * 16 + fr;
          O[((size_t)(b * L_ + qrow)) * 2048 + h * 64 + d] =
              f2bf_hw(oacc[s][nf][j] * inv);
        }
      }
  }
}

extern "C" void kernel_launch(void* const* d_in, const int* in_sizes, int n_in,
                              void* d_out, int out_size, void* d_ws, size_t ws_size,
                              hipStream_t stream) {
  (void)in_sizes; (void)n_in; (void)out_size; (void)ws_size;
  const float* x  = (const float*)d_in[0];
  const float* wq = (const float*)d_in[1];
  const float* wk = (const float*)d_in[2];
  const float* wv = (const float*)d_in[3];
  const float* wo = (const float*)d_in[4];
  const float* fc = (const float*)d_in[5];
  const float* fs = (const float*)d_in[6];
  float* out = (float*)d_out;

  char* ws = (char*)d_ws;
  unsigned short* x_b  = (unsigned short*)(ws + 0);           // 16 MiB
  unsigned short* wT   = (unsigned short*)(ws + 16777216);    // 12 MiB [3072][2048]
  unsigned short* woT  = (unsigned short*)(ws + 29360128);    // 8 MiB
  float* qkv_f         = (float*)(ws + 37748736);             // 48 MiB [4096][3072]
  unsigned short* at_b = (unsigned short*)(ws + 37748736);    // aliases qkv_f (safe)
  unsigned short* q_b  = (unsigned short*)(ws + 88080384);    // 16 MiB
  unsigned short* k_b  = (unsigned short*)(ws + 104857600);   // 4 MiB
  unsigned short* vT_b = (unsigned short*)(ws + 109051904);   // 4 MiB

  const float qscale = 0.125f * 1.4426950408889634f;

  // allow 128 KiB dynamic LDS for the 256^2 GEMM (idempotent, non-stream op)
  hipFuncSetAttribute((const void*)gemm256_kernel,
                      hipFuncAttributeMaxDynamicSharedMemorySize, 131072);

  dim3 tb(32, 8);
  cast_bf16_kernel<<<8192, 256, 0, stream>>>(x, x_b, M_ * D_ / 4);
  transpose_cast_kernel<<<dim3(64, 64), tb, 0, stream>>>(wq, wT, 2048, 2048);
  transpose_cast_kernel<<<dim3(16, 64), tb, 0, stream>>>(wk, wT + (size_t)2048 * 2048, 2048, 512);
  transpose_cast_kernel<<<dim3(16, 64), tb, 0, stream>>>(wv, wT + (size_t)2560 * 2048, 2048, 512);
  transpose_cast_kernel<<<dim3(64, 64), tb, 0, stream>>>(wo, woT, 2048, 2048);

  gemm256_kernel<<<dim3(NF_ / 256, M_ / 256), 512, 131072, stream>>>(
      x_b, wT, qkv_f, M_, NF_, 2048);

  rope_kernel<<<16384, 256, 0, stream>>>(qkv_f, fc, fs, q_b, 32, 0, qscale, M_ * 32 * 32);
  rope_kernel<<<4096, 256, 0, stream>>>(qkv_f, fc, fs, k_b, 8, 2048, 1.0f, M_ * 8 * 32);
  cast_vT_kernel<<<dim3(64, 2, 16), tb, 0, stream>>>(qkv_f, vT_b);

  attn_kernel<<<dim3(64, 8), 256, 0, stream>>>(q_b, k_b, vT_b, at_b);

  gemm256_kernel<<<dim3(2048 / 256, M_ / 256), 512, 131072, stream>>>(
      at_b, woT, out, M_, 2048, 2048);
}